// Round 10
// baseline (415.891 us; speedup 1.0000x reference)
//
#include <hip/hip_runtime.h>
#include <stdint.h>

#define NBATCH 16384
#define TT     20
#define CC     256
#define FP     260   // f32 LDS row stride: 1040B -> rows shift 4 banks (2-way on b128, free)
#define LDK    264   // sT row stride (u16): 528B
#define TP     40    // sVT inner stride (u16): 80B
#define NT     512   // 8 waves
#define BPB    64    // batches per block; grid = 256 = 1 block/CU

typedef __bf16 bf16x8 __attribute__((ext_vector_type(8)));
typedef float  f32x4  __attribute__((ext_vector_type(4)));

#define GLL16(g, l) __builtin_amdgcn_global_load_lds( \
    (const __attribute__((address_space(1))) uint32_t*)(g), \
    (__attribute__((address_space(3))) uint32_t*)(l), 16, 0, 0)

#define BAR_LGKM() do { asm volatile("s_waitcnt lgkmcnt(0)" ::: "memory"); \
                        __builtin_amdgcn_s_barrier(); } while (0)
#define BAR_VM0()  do { asm volatile("s_waitcnt vmcnt(0) lgkmcnt(0)" ::: "memory"); \
                        __builtin_amdgcn_s_barrier(); } while (0)

// tb_mask tables: t=0,1:{0,1,2} t=2:{0,1,2,3} t=3..15:{t,t+1} t=16:uniform t=17..19:{17,18,19}
__constant__ int8_t c_CNT[TT] = {3,3,4,2,2,2,2,2,2,2,2,2,2,2,2,2,0,3,3,3};
__constant__ int8_t c_OFF[TT] = {0,3,6,10,12,14,16,18,20,22,24,26,28,30,32,34,0,36,39,42};
__constant__ int8_t c_PT[45]  = {0,0,0,1,1,1,2,2,2,2,3,3,4,4,5,5,6,6,7,7,8,8,9,9,
                                 10,10,11,11,12,12,13,13,14,14,15,15,17,17,17,18,18,18,19,19,19};
__constant__ int8_t c_PS[45]  = {0,1,2,0,1,2,0,1,2,3,3,4,4,5,5,6,6,7,7,8,8,9,9,10,
                                 10,11,11,12,12,13,13,14,14,15,15,16,17,18,19,17,18,19,17,18,19};

__device__ __forceinline__ uint16_t f2bf(float f) {
    __bf16 b = (__bf16)f;
    return __builtin_bit_cast(uint16_t, b);
}
__device__ __forceinline__ uint32_t pk2(float a, float b) {
    return (uint32_t)f2bf(a) | ((uint32_t)f2bf(b) << 16);
}
__device__ __forceinline__ float bflo(uint32_t u) { return __builtin_bit_cast(float, u << 16); }
__device__ __forceinline__ float bfhi(uint32_t u) { return __builtin_bit_cast(float, u & 0xffff0000u); }

// prep1: mqkT[n][k] = sum_h Wk[h,n]*Wq[h,k] / 16 ;  wvb[n][k] = bf16(Wv[n][k])
__global__ void prep1_kernel(const float* __restrict__ Wq, const float* __restrict__ Wk,
                             const float* __restrict__ Wv, uint16_t* __restrict__ mqkT,
                             uint16_t* __restrict__ wvb) {
    const int n = blockIdx.x;
    const int k = threadIdx.x;
    float acc = 0.f;
    for (int h = 0; h < CC; ++h)
        acc = fmaf(Wk[h * CC + n], Wq[h * CC + k], acc);
    mqkT[n * CC + k] = f2bf(acc * 0.0625f);
    wvb[n * CC + k]  = f2bf(Wv[n * CC + k]);
}

// prep2: fragment order for 8 waves x 32 cols: frag (w*16 + kk*2 + mt), lane holds
// src[n = w*32+mt*16+(lane&15)][col = kk*32+((lane>>4)<<3) .. +8]
__global__ void prep2_kernel(const uint16_t* __restrict__ mqkT, const uint16_t* __restrict__ wvb,
                             uint16_t* __restrict__ BqS, uint16_t* __restrict__ BvS) {
    const int bid = blockIdx.x;          // 0..127 : m*64 + w*8 + kk
    const int m  = bid >> 6;
    const int w  = (bid >> 3) & 7;
    const int kk = bid & 7;
    const int mt   = threadIdx.x >> 6;   // block 128 threads
    const int lane = threadIdx.x & 63;
    const uint16_t* src = m ? wvb : mqkT;
    uint16_t*       dst = m ? BvS : BqS;
    const int n   = w * 32 + mt * 16 + (lane & 15);
    const int col = kk * 32 + ((lane >> 4) << 3);
    uint4 v = *(const uint4*)(src + n * CC + col);
    *(uint4*)(dst + ((size_t)((w * 16 + kk * 2 + mt) * 64 + lane) << 3)) = v;
}

// 8 f32 at row r, unit u (8-f32 granule) -> bf16x8 (no swizzle; FP stride spreads banks)
__device__ __forceinline__ bf16x8 ldsAf(const float* __restrict__ sF, int r, int u) {
    const float* p = sF + r * FP + (u << 3);
    float4 lo = *(const float4*)p;
    float4 hi = *(const float4*)(p + 4);
    uint4 q;
    q.x = pk2(lo.x, lo.y); q.y = pk2(lo.z, lo.w);
    q.z = pk2(hi.x, hi.y); q.w = pk2(hi.z, hi.w);
    return __builtin_bit_cast(bf16x8, q);
}

__global__ __launch_bounds__(NT, 2)
void attn_main(const float* __restrict__ f1g, const float* __restrict__ f2g,
               const uint16_t* __restrict__ BqS, const uint16_t* __restrict__ BvS,
               float* __restrict__ outg) {
    __shared__ float    sF1[2][TT * FP];   // feat1 f32, double-buffered (DMA)
    __shared__ float    sF2[2][TT * FP];   // feat2 f32, double-buffered (DMA)
    __shared__ uint16_t sT [TT * LDK];     // t1 bf16 [t][h]
    __shared__ uint16_t sVT[256 * TP];     // v^T bf16 [h][t]
    __shared__ uint16_t attnL[32 * 32];    // exp-weights, padded
    __shared__ float    s_simE[45];

    const int tid  = threadIdx.x;
    const int lane = tid & 63;
    const int w    = tid >> 6;             // 0..7, wave owns 32 hid cols
    const int l15  = lane & 15;
    const int q    = lane >> 4;
    const size_t blockBase = (size_t)blockIdx.x * BPB * TT * CC;

    // ---- weights resident in VGPRs (128 regs), loaded once ----
    bf16x8 Bq[2][8], Bv[2][8];
#pragma unroll
    for (int kk = 0; kk < 8; ++kk)
#pragma unroll
        for (int mt = 0; mt < 2; ++mt) {
            const size_t idx = ((size_t)((w * 16 + kk * 2 + mt) * 64 + lane)) << 3;
            Bq[mt][kk] = __builtin_bit_cast(bf16x8, *(const uint4*)(BqS + idx));
            Bv[mt][kk] = __builtin_bit_cast(bf16x8, *(const uint4*)(BvS + idx));
        }

    // per-wave DMA role: waves 0-3 stage feat1 rows, waves 4-7 stage feat2 rows
    const float* srcTen = (w < 4 ? f1g : f2g) + blockBase;
    const int rw = (w & 3) * 5;

    // ---- prologue: DMA tile 0 -> buf 0; prefill attnL ----
#pragma unroll
    for (int j = 0; j < 5; ++j) {
        int r = rw + j;
        GLL16(srcTen + r * 256 + (lane << 2), (w < 4 ? sF1[0] : sF2[0]) + r * FP);
    }
    {   // attnL: zeros; row16 cols0..19 = 1.0 (uniform row); 512 u32 slots, 1/thread
        uint32_t* aL = (uint32_t*)attnL;
        aL[tid] = ((tid >> 4) == 16 && (tid & 15) < 10) ? 0x3F803F80u : 0u;
    }
    BAR_VM0();

    const int rB0 = l15;
    const int rB1 = (16 + l15 < TT) ? 16 + l15 : TT - 1;

    for (int i = 0; i < BPB; ++i) {
        const int cur = i & 1, nxt = cur ^ 1;

        // ---- top: issue next tile's DMA (stays in flight until BAR_VM0) ----
        if (i + 1 < BPB) {
            const float* sp = srcTen + (size_t)(i + 1) * TT * CC;
            float* dp = (w < 4 ? sF1[nxt] : sF2[nxt]);
#pragma unroll
            for (int j = 0; j < 5; ++j) {
                int r = rw + j;
                GLL16(sp + r * 256 + (lane << 2), dp + r * FP);
            }
        }
        const float* F1 = sF1[cur];
        const float* F2 = sF2[cur];

        // ---- phase A: GEMM1 swapped (A=Mqk frags, B=feat1) -> t1^T -> sT ----
        {
            f32x4 acc[2][2];
#pragma unroll
            for (int mt = 0; mt < 2; ++mt)
#pragma unroll
                for (int ct = 0; ct < 2; ++ct)
                    acc[mt][ct] = f32x4{0.f, 0.f, 0.f, 0.f};
#pragma unroll
            for (int kk = 0; kk < 8; ++kk) {
                const int u = (kk << 2) + q;
                bf16x8 b0 = ldsAf(F1, rB0, u);
                bf16x8 b1 = ldsAf(F1, rB1, u);
#pragma unroll
                for (int mt = 0; mt < 2; ++mt) {
                    acc[mt][0] = __builtin_amdgcn_mfma_f32_16x16x32_bf16(Bq[mt][kk], b0, acc[mt][0], 0, 0, 0);
                    acc[mt][1] = __builtin_amdgcn_mfma_f32_16x16x32_bf16(Bq[mt][kk], b1, acc[mt][1], 0, 0, 0);
                }
            }
            // D: lane holds t1^T[h = w*32+mt*16+4q+j][t = ct*16+l15] -> sT[t][h]
#pragma unroll
            for (int mt = 0; mt < 2; ++mt)
#pragma unroll
                for (int ct = 0; ct < 2; ++ct) {
                    int t = ct * 16 + l15;
                    if (t < TT) {
                        int h0 = (w << 5) + mt * 16 + (q << 2);
                        uint2 u2;
                        u2.x = pk2(acc[mt][ct][0], acc[mt][ct][1]);
                        u2.y = pk2(acc[mt][ct][2], acc[mt][ct][3]);
                        *(uint2*)&sT[t * LDK + h0] = u2;
                    }
                }
        }
        BAR_LGKM();   // A: sT visible; prefetch DMA still in flight

        // ---- phase B: sim+exp (360 thr) and GEMM2 -> sVT ----
        if (tid < 360) {
            int d = tid >> 3, p = tid & 7;
            int t = c_PT[d], s = c_PS[d];
            const uint16_t* ap = sT + t * LDK + (p << 5);
            const float*    bp = F2 + s * FP + (p << 5);
            float da = 0.f;
#pragma unroll
            for (int jj = 0; jj < 4; ++jj) {
                uint4 ua = *(const uint4*)(ap + (jj << 3));
                float4 lo = *(const float4*)(bp + (jj << 3));
                float4 hi = *(const float4*)(bp + (jj << 3) + 4);
                da = fmaf(bflo(ua.x), lo.x, da);
                da = fmaf(bfhi(ua.x), lo.y, da);
                da = fmaf(bflo(ua.y), lo.z, da);
                da = fmaf(bfhi(ua.y), lo.w, da);
                da = fmaf(bflo(ua.z), hi.x, da);
                da = fmaf(bfhi(ua.z), hi.y, da);
                da = fmaf(bflo(ua.w), hi.z, da);
                da = fmaf(bfhi(ua.w), hi.w, da);
            }
            da += __shfl_xor(da, 1);
            da += __shfl_xor(da, 2);
            da += __shfl_xor(da, 4);
            if (p == 0) {
                float e = __expf(da);
                attnL[t * 32 + s] = f2bf(e);
                s_simE[d] = e;
            }
        }
        {
            f32x4 av[2][2];
#pragma unroll
            for (int rt = 0; rt < 2; ++rt)
#pragma unroll
                for (int ct = 0; ct < 2; ++ct)
                    av[rt][ct] = f32x4{0.f, 0.f, 0.f, 0.f};
#pragma unroll
            for (int kk = 0; kk < 8; ++kk) {
                const int u = (kk << 2) + q;
                bf16x8 a0 = ldsAf(F2, rB0, u);
                bf16x8 a1 = ldsAf(F2, rB1, u);
#pragma unroll
                for (int ct = 0; ct < 2; ++ct) {
                    av[0][ct] = __builtin_amdgcn_mfma_f32_16x16x32_bf16(a0, Bv[ct][kk], av[0][ct], 0, 0, 0);
                    av[1][ct] = __builtin_amdgcn_mfma_f32_16x16x32_bf16(a1, Bv[ct][kk], av[1][ct], 0, 0, 0);
                }
            }
            // D: v[t = rt*16+4q+j][h = w*32+ct*16+l15] -> sVT[h][t]; zero t=20..31 lanes
#pragma unroll
            for (int ct = 0; ct < 2; ++ct) {
                int h = (w << 5) + ct * 16 + l15;
                {
                    uint2 u2;
                    u2.x = pk2(av[0][ct][0], av[0][ct][1]);
                    u2.y = pk2(av[0][ct][2], av[0][ct][3]);
                    *(uint2*)&sVT[h * TP + (q << 2)] = u2;
                }
                {
                    uint2 u2;
                    if (q == 0) {
                        u2.x = pk2(av[1][ct][0], av[1][ct][1]);
                        u2.y = pk2(av[1][ct][2], av[1][ct][3]);
                    } else { u2.x = 0u; u2.y = 0u; }
                    *(uint2*)&sVT[h * TP + 16 + (q << 2)] = u2;
                }
            }
        }
        BAR_VM0();    // B: sVT/attnL/simE visible; next-tile DMA guaranteed complete

        // ---- phase C: PV via MFMA + normalize-at-store ----
        {
            bf16x8 pa0 = __builtin_bit_cast(bf16x8, *(const uint4*)&attnL[l15 * 32 + (q << 3)]);
            bf16x8 pa1 = __builtin_bit_cast(bf16x8, *(const uint4*)&attnL[(16 + l15) * 32 + (q << 3)]);
            const f32x4 z = f32x4{0.f, 0.f, 0.f, 0.f};
            f32x4 o[2][2];
#pragma unroll
            for (int ct = 0; ct < 2; ++ct) {
                bf16x8 pb = __builtin_bit_cast(bf16x8,
                    *(const uint4*)&sVT[((w << 5) + ct * 16 + l15) * TP + (q << 3)]);
                o[0][ct] = __builtin_amdgcn_mfma_f32_16x16x32_bf16(pa0, pb, z, 0, 0, 0);
                o[1][ct] = __builtin_amdgcn_mfma_f32_16x16x32_bf16(pa1, pb, z, 0, 0, 0);
            }
            const size_t ob = blockBase + (size_t)i * TT * CC;
#pragma unroll
            for (int rt = 0; rt < 2; ++rt)
#pragma unroll
                for (int j = 0; j < 4; ++j) {
                    int t = rt * 16 + (q << 2) + j;
                    if (t < TT) {
                        int cnt = c_CNT[t], off = c_OFF[t];
                        float rs = (cnt == 0) ? 20.0f : s_simE[off];
#pragma unroll
                        for (int jj = 1; jj < 4; ++jj)
                            if (jj < cnt) rs += s_simE[off + jj];
                        float iv = __builtin_amdgcn_rcpf(rs);
                        float* op = outg + ob + (size_t)t * CC + (w << 5) + l15;
                        op[0]  = o[rt][0][j] * iv;
                        op[16] = o[rt][1][j] * iv;
                    }
                }
        }
        // no third barrier: next iter's GEMM1 touches only buf[nxt] (DMA-confirmed at BAR_VM0)
        // and sT (whose readers finished before BAR_VM0); PV readers finish before next BAR_LGKM.
    }
}

extern "C" void kernel_launch(void* const* d_in, const int* in_sizes, int n_in,
                              void* d_out, int out_size, void* d_ws, size_t ws_size,
                              hipStream_t stream) {
    const float* feat1 = (const float*)d_in[0];
    const float* feat2 = (const float*)d_in[1];
    const float* Wq    = (const float*)d_in[2];
    const float* Wk    = (const float*)d_in[3];
    const float* Wv    = (const float*)d_in[4];
    uint16_t* mqkT = (uint16_t*)d_ws;          // 128 KB
    uint16_t* wvb  = mqkT + CC * CC;           // 128 KB
    uint16_t* BqS  = wvb  + CC * CC;           // 128 KB (fragment-ordered)
    uint16_t* BvS  = BqS  + CC * CC;           // 128 KB (fragment-ordered)

    prep1_kernel<<<CC, CC, 0, stream>>>(Wq, Wk, Wv, mqkT, wvb);
    prep2_kernel<<<128, 128, 0, stream>>>(mqkT, wvb, BqS, BvS);
    attn_main<<<NBATCH / BPB, NT, 0, stream>>>(feat1, feat2, BqS, BvS, (float*)d_out);
}